// Round 4
// baseline (137.111 us; speedup 1.0000x reference)
//
#include <hip/hip_runtime.h>
#include <math.h>

typedef float f4 __attribute__((ext_vector_type(4)));

// ---------------------------------------------------------------------------
// Fused single-dispatch kernel, latency-optimized prologue + software-
// pipelined streaming loop.
//
// Round-3 counters (first time our kernel was visible): 41.4 us, 2.42 TB/s
// (30% peak), VALUBusy 29.6%. Diagnosis: per-iteration load->use->NT-store
// creates a vmcnt FIFO chain where each use waits on the PREVIOUS iteration's
// nontemporal store completing at HBM (NT bypasses L2 -> slow completion).
// 533cy stall vs 160cy VALU per round == the measured 30% VALUBusy.
//
// Fix: (a) plain stores -> completion at L2 (~100cy; the 6.4 TB/s fill
// kernel proves plain stores are the fast path), (b) prefetch-by-1 pipeline
// so the waitcnt before each use leaves the newest load + store in flight.
//
// Params P[16]:
//   P[0..3]   : P0 cubic coeffs (c0,c1,c2,c3) in global x (interval 0, tk=0)
//   P[4..9]   : interior knots k1..k6
//   P[10..15] : e1..e6, the x^3-coefficient jumps across k1..k6
//
// f(xq) = P0(xq) + sum_j e_j * max(0, xq-k_j)^3   (C^2 spline identity)
// ---------------------------------------------------------------------------

__device__ __forceinline__ float eval_one(float xv,
                                          float c0, float c1, float c2, float c3,
                                          float k1, float k2, float k3,
                                          float k4, float k5, float k6,
                                          float e1, float e2, float e3,
                                          float e4, float e5, float e6)
{
    const float xq = fminf(fmaxf(xv * 0.57735026918962576f, 0.0f), 0.9999f);
    float acc = fmaf(fmaf(fmaf(c3, xq, c2), xq, c1), xq, c0);
    float r;
    r = fmaxf(xq - k1, 0.f); acc = fmaf(e1 * r, r * r, acc);
    r = fmaxf(xq - k2, 0.f); acc = fmaf(e2 * r, r * r, acc);
    r = fmaxf(xq - k3, 0.f); acc = fmaf(e3 * r, r * r, acc);
    r = fmaxf(xq - k4, 0.f); acc = fmaf(e4 * r, r * r, acc);
    r = fmaxf(xq - k5, 0.f); acc = fmaf(e5 * r, r * r, acc);
    r = fmaxf(xq - k6, 0.f); acc = fmaf(e6 * r, r * r, acc);
    return acc;
}

__global__ __launch_bounds__(256) void nsf_fused_kernel(
        const float* __restrict__ x,
        const float* __restrict__ a,
        const float* __restrict__ W1, const float* __restrict__ b1,
        const float* __restrict__ W2, const float* __restrict__ b2,
        const float* __restrict__ Ww, const float* __restrict__ bw,
        const float* __restrict__ Wk, const float* __restrict__ bk,
        float* __restrict__ out, int n)
{
    __shared__ float sW1[16], sb1[16], sW2[256], sb2[16], sWw[144], sbw[9], sWk[112], sbk[7], sa;
    __shared__ float n1[16], n2[16], wv[9], krs[7], t[14], cc[10], d3[7], p0[4], P[16];
    const int tid = threadIdx.x;

    // ---- one-round parallel prefetch (threads 0..63 load all 577 weights,
    //      every load independent -> single global-latency exposure) ----
    if (tid < 64) {
        reinterpret_cast<f4*>(sW2)[tid] = reinterpret_cast<const f4*>(W2)[tid];   // 256 floats
        if (tid < 36) reinterpret_cast<f4*>(sWw)[tid] = reinterpret_cast<const f4*>(Ww)[tid];  // 144
        if (tid < 28) reinterpret_cast<f4*>(sWk)[tid] = reinterpret_cast<const f4*>(Wk)[tid];  // 112
        if (tid < 4)       reinterpret_cast<f4*>(sW1)[tid]     = reinterpret_cast<const f4*>(W1)[tid];
        else if (tid < 8)  reinterpret_cast<f4*>(sb1)[tid - 4] = reinterpret_cast<const f4*>(b1)[tid - 4];
        else if (tid < 12) reinterpret_cast<f4*>(sb2)[tid - 8] = reinterpret_cast<const f4*>(b2)[tid - 8];
        if (tid >= 36 && tid < 45) sbw[tid - 36] = bw[tid - 36];
        if (tid >= 45 && tid < 52) sbk[tid - 45] = bk[tid - 45];
        if (tid == 52) sa = a[0];
    }
    __syncthreads();

    // ---- MLP (LDS-resident) ----
    if (tid < 16) n1[tid] = sinf(sa * sW1[tid] + sb1[tid]);
    __syncthreads();

    if (tid < 16) {
        float s = sb2[tid];
        for (int i = 0; i < 16; ++i) s += n1[i] * sW2[i * 16 + tid];
        n2[tid] = sinf(s);
    }
    __syncthreads();

    if (tid < 9) {
        float s = sbw[tid];
        for (int i = 0; i < 16; ++i) s += n2[i] * sWw[i * 9 + tid];
        wv[tid] = s;
    }
    if (tid >= 16 && tid < 23) {
        const int j = tid - 16;
        float s = sbk[j];
        for (int i = 0; i < 16; ++i) s += n2[i] * sWk[i * 7 + j];
        krs[j] = s;
    }
    __syncthreads();

    if (tid == 0) {
        // softmax + cumsum -> strictly increasing interior knots in (0,1]
        float m = krs[0];
        for (int j = 1; j < 7; ++j) m = fmaxf(m, krs[j]);
        float e[7], se = 0.f;
        for (int j = 0; j < 7; ++j) { e[j] = expf(krs[j] - m); se += e[j]; }
        const float inv = 1.f / se;
        t[0] = t[1] = t[2] = t[3] = 0.f;
        float cum = 0.f;
        for (int j = 0; j < 7; ++j) { cum += e[j] * inv; t[4 + j] = cum; }
        t[11] = t[12] = t[13] = 1.f;
        cc[0] = 0.f;
        for (int j = 0; j < 9; ++j) cc[1 + j] = wv[j];
    }
    __syncthreads();

    if (tid < 7) {
        // Symbolic de Boor for interval tid (knot span k = 3+tid), polynomial
        // in u = xq - t[k]. alpha = (xq - tlo)/(thi - tlo) = A + B*u;
        // every denominator spans >= 1 interior knot gap -> strictly > 0.
        const int k = 3 + tid;
        const float tk = t[k];
        float d[4][4];
        for (int j = 0; j < 4; ++j) {
            d[j][0] = cc[k - 3 + j];
            d[j][1] = d[j][2] = d[j][3] = 0.f;
        }
        for (int r = 1; r <= 3; ++r) {
            for (int j = 3; j >= r; --j) {
                const float tlo = t[k + j - 3];
                const float thi = t[k + j + 1 - r];
                const float B = 1.f / (thi - tlo);
                const float A = (tk - tlo) * B;
                float nd[4];
                for (int nn = 0; nn < 4; ++nn) nd[nn] = d[j - 1][nn];
                for (int nn = 0; nn < r; ++nn) {
                    const float en = d[j][nn] - d[j - 1][nn];
                    nd[nn]     += A * en;
                    nd[nn + 1] += B * en;
                }
                for (int nn = 0; nn < 4; ++nn) d[j][nn] = nd[nn];
            }
        }
        d3[tid] = d[3][3];
        if (tid == 0) {   // interval 0 has tk = 0 -> already expanded in x
            p0[0] = d[3][0]; p0[1] = d[3][1]; p0[2] = d[3][2]; p0[3] = d[3][3];
        }
    }
    __syncthreads();

    if (tid < 16) {
        float val;
        if (tid < 4)       val = p0[tid];
        else if (tid < 10) val = t[tid];                      // t[4..9] == k1..k6
        else               val = d3[tid - 9] - d3[tid - 10];  // e_{tid-9}
        P[tid] = val;
    }
    __syncthreads();

    // ---- broadcast params to registers (wave-uniform LDS reads) ----
    const float c0 = P[0],  c1 = P[1],  c2 = P[2],  c3 = P[3];
    const float k1 = P[4],  k2 = P[5],  k3 = P[6],  k4 = P[7],  k5 = P[8],  k6 = P[9];
    const float e1 = P[10], e2 = P[11], e3 = P[12], e4 = P[13], e5 = P[14], e6 = P[15];

    // ---- streaming eval: prefetch-by-1 software pipeline, plain stores ----
    const int n4 = n >> 2;
    const int gid = blockIdx.x * blockDim.x + tid;
    const int stride = gridDim.x * blockDim.x;

    const f4* __restrict__ x4 = reinterpret_cast<const f4*>(x);
    f4* __restrict__ o4 = reinterpret_cast<f4*>(out);

    int idx = gid;
    if (idx < n4) {
        f4 v = x4[idx];                       // prologue load
        int next = idx + stride;
        for (; next < n4; next += stride) {
            const f4 vn = x4[next];           // issue next load BEFORE using v
            f4 r;
            r.x = eval_one(v.x, c0,c1,c2,c3, k1,k2,k3,k4,k5,k6, e1,e2,e3,e4,e5,e6);
            r.y = eval_one(v.y, c0,c1,c2,c3, k1,k2,k3,k4,k5,k6, e1,e2,e3,e4,e5,e6);
            r.z = eval_one(v.z, c0,c1,c2,c3, k1,k2,k3,k4,k5,k6, e1,e2,e3,e4,e5,e6);
            r.w = eval_one(v.w, c0,c1,c2,c3, k1,k2,k3,k4,k5,k6, e1,e2,e3,e4,e5,e6);
            o4[idx] = r;                      // plain store: completes at L2
            v = vn;
            idx = next;
        }
        // epilogue: last element
        f4 r;
        r.x = eval_one(v.x, c0,c1,c2,c3, k1,k2,k3,k4,k5,k6, e1,e2,e3,e4,e5,e6);
        r.y = eval_one(v.y, c0,c1,c2,c3, k1,k2,k3,k4,k5,k6, e1,e2,e3,e4,e5,e6);
        r.z = eval_one(v.z, c0,c1,c2,c3, k1,k2,k3,k4,k5,k6, e1,e2,e3,e4,e5,e6);
        r.w = eval_one(v.w, c0,c1,c2,c3, k1,k2,k3,k4,k5,k6, e1,e2,e3,e4,e5,e6);
        o4[idx] = r;
    }
    // scalar tail (n % 4 != 0 safety; empty at n = 256^3)
    for (int j = (n4 << 2) + gid; j < n; j += stride)
        out[j] = eval_one(x[j], c0,c1,c2,c3, k1,k2,k3,k4,k5,k6, e1,e2,e3,e4,e5,e6);
}

extern "C" void kernel_launch(void* const* d_in, const int* in_sizes, int n_in,
                              void* d_out, int out_size, void* d_ws, size_t ws_size,
                              hipStream_t stream)
{
    const float* x  = (const float*)d_in[0];
    const float* a  = (const float*)d_in[1];
    const float* W1 = (const float*)d_in[2];
    const float* b1 = (const float*)d_in[3];
    const float* W2 = (const float*)d_in[4];
    const float* b2 = (const float*)d_in[5];
    const float* Ww = (const float*)d_in[6];
    const float* bw = (const float*)d_in[7];
    const float* Wk = (const float*)d_in[8];
    const float* bk = (const float*)d_in[9];
    float* out = (float*)d_out;
    const int n = out_size;

    // Single fused dispatch: 2048 blocks x 256 = 8192 waves (32/CU capacity);
    // 8 float4/thread. Params computed redundantly per block via one-round
    // LDS prefetch (all loads independent).
    hipLaunchKernelGGL(nsf_fused_kernel, dim3(2048), dim3(256), 0, stream,
                       x, a, W1, b1, W2, b2, Ww, bw, Wk, bk, out, n);
}

// Round 5
// 129.924 us; speedup vs baseline: 1.0553x; 1.0553x over previous
//
#include <hip/hip_runtime.h>
#include <math.h>

typedef float f4 __attribute__((ext_vector_type(4)));

// ---------------------------------------------------------------------------
// Fused single-dispatch kernel.
//   Prologue: one-round LDS prefetch of all 577 weights -> LDS-resident MLP
//             -> softmax/cumsum knots -> symbolic de Boor -> P[16].
//   Stream:   pair-wide software pipeline (2 independent f4 loads in flight),
//             NONTEMPORAL stores.
//
// Round-4 lessons baked in:
//   * NT stores, not plain: plain stores defer ~32MB of dirty-L2 writeback
//     into the next dispatch (graph dur_us regressed 131.5->137.1 while the
//     profiled kernel got faster) — rocprof replay hides writeback, graph
//     timing doesn't. R0/R3 (best rounds) both used NT.
//   * Pipeline order load(next) -> eval(cur) -> NT-store(cur): the vmcnt wait
//     before eval leaves the NT stores in flight (FIFO: stores are newer than
//     the loads being waited on).
//   * 1024 blocks x 16 f4/thread: halves redundant prologues; streaming BW
//     needs little occupancy (fills hit 6.5 TB/s at 8%).
//
// Params P[16]:
//   P[0..3]   : P0 cubic coeffs (c0,c1,c2,c3) in global x (interval 0, tk=0)
//   P[4..9]   : interior knots k1..k6
//   P[10..15] : e1..e6, the x^3-coefficient jumps across k1..k6
//
// f(xq) = P0(xq) + sum_j e_j * max(0, xq-k_j)^3   (C^2 spline identity)
// ---------------------------------------------------------------------------

__device__ __forceinline__ float eval_one(float xv,
                                          float c0, float c1, float c2, float c3,
                                          float k1, float k2, float k3,
                                          float k4, float k5, float k6,
                                          float e1, float e2, float e3,
                                          float e4, float e5, float e6)
{
    const float xq = fminf(fmaxf(xv * 0.57735026918962576f, 0.0f), 0.9999f);
    float acc = fmaf(fmaf(fmaf(c3, xq, c2), xq, c1), xq, c0);
    float r;
    r = fmaxf(xq - k1, 0.f); acc = fmaf(e1 * r, r * r, acc);
    r = fmaxf(xq - k2, 0.f); acc = fmaf(e2 * r, r * r, acc);
    r = fmaxf(xq - k3, 0.f); acc = fmaf(e3 * r, r * r, acc);
    r = fmaxf(xq - k4, 0.f); acc = fmaf(e4 * r, r * r, acc);
    r = fmaxf(xq - k5, 0.f); acc = fmaf(e5 * r, r * r, acc);
    r = fmaxf(xq - k6, 0.f); acc = fmaf(e6 * r, r * r, acc);
    return acc;
}

#define EVAL4(dst, src)                                                          \
    do {                                                                         \
        dst.x = eval_one(src.x, c0,c1,c2,c3, k1,k2,k3,k4,k5,k6, e1,e2,e3,e4,e5,e6); \
        dst.y = eval_one(src.y, c0,c1,c2,c3, k1,k2,k3,k4,k5,k6, e1,e2,e3,e4,e5,e6); \
        dst.z = eval_one(src.z, c0,c1,c2,c3, k1,k2,k3,k4,k5,k6, e1,e2,e3,e4,e5,e6); \
        dst.w = eval_one(src.w, c0,c1,c2,c3, k1,k2,k3,k4,k5,k6, e1,e2,e3,e4,e5,e6); \
    } while (0)

__global__ __launch_bounds__(256) void nsf_fused_kernel(
        const float* __restrict__ x,
        const float* __restrict__ a,
        const float* __restrict__ W1, const float* __restrict__ b1,
        const float* __restrict__ W2, const float* __restrict__ b2,
        const float* __restrict__ Ww, const float* __restrict__ bw,
        const float* __restrict__ Wk, const float* __restrict__ bk,
        float* __restrict__ out, int n)
{
    __shared__ float sW1[16], sb1[16], sW2[256], sb2[16], sWw[144], sbw[9], sWk[112], sbk[7], sa;
    __shared__ float n1[16], n2[16], wv[9], krs[7], t[14], cc[10], d3[7], p0[4], P[16];
    const int tid = threadIdx.x;

    // ---- one-round parallel prefetch (threads 0..63 load all 577 weights,
    //      every load independent -> single global-latency exposure) ----
    if (tid < 64) {
        reinterpret_cast<f4*>(sW2)[tid] = reinterpret_cast<const f4*>(W2)[tid];   // 256 floats
        if (tid < 36) reinterpret_cast<f4*>(sWw)[tid] = reinterpret_cast<const f4*>(Ww)[tid];  // 144
        if (tid < 28) reinterpret_cast<f4*>(sWk)[tid] = reinterpret_cast<const f4*>(Wk)[tid];  // 112
        if (tid < 4)       reinterpret_cast<f4*>(sW1)[tid]     = reinterpret_cast<const f4*>(W1)[tid];
        else if (tid < 8)  reinterpret_cast<f4*>(sb1)[tid - 4] = reinterpret_cast<const f4*>(b1)[tid - 4];
        else if (tid < 12) reinterpret_cast<f4*>(sb2)[tid - 8] = reinterpret_cast<const f4*>(b2)[tid - 8];
        if (tid >= 36 && tid < 45) sbw[tid - 36] = bw[tid - 36];
        if (tid >= 45 && tid < 52) sbk[tid - 45] = bk[tid - 45];
        if (tid == 52) sa = a[0];
    }
    __syncthreads();

    // ---- MLP (LDS-resident) ----
    if (tid < 16) n1[tid] = sinf(sa * sW1[tid] + sb1[tid]);
    __syncthreads();

    if (tid < 16) {
        float s = sb2[tid];
        for (int i = 0; i < 16; ++i) s += n1[i] * sW2[i * 16 + tid];
        n2[tid] = sinf(s);
    }
    __syncthreads();

    if (tid < 9) {
        float s = sbw[tid];
        for (int i = 0; i < 16; ++i) s += n2[i] * sWw[i * 9 + tid];
        wv[tid] = s;
    }
    if (tid >= 16 && tid < 23) {
        const int j = tid - 16;
        float s = sbk[j];
        for (int i = 0; i < 16; ++i) s += n2[i] * sWk[i * 7 + j];
        krs[j] = s;
    }
    __syncthreads();

    if (tid == 0) {
        // softmax + cumsum -> strictly increasing interior knots in (0,1]
        float m = krs[0];
        for (int j = 1; j < 7; ++j) m = fmaxf(m, krs[j]);
        float e[7], se = 0.f;
        for (int j = 0; j < 7; ++j) { e[j] = expf(krs[j] - m); se += e[j]; }
        const float inv = 1.f / se;
        t[0] = t[1] = t[2] = t[3] = 0.f;
        float cum = 0.f;
        for (int j = 0; j < 7; ++j) { cum += e[j] * inv; t[4 + j] = cum; }
        t[11] = t[12] = t[13] = 1.f;
        cc[0] = 0.f;
        for (int j = 0; j < 9; ++j) cc[1 + j] = wv[j];
    }
    __syncthreads();

    if (tid < 7) {
        // Symbolic de Boor for interval tid (knot span k = 3+tid), polynomial
        // in u = xq - t[k]. alpha = (xq - tlo)/(thi - tlo) = A + B*u;
        // every denominator spans >= 1 interior knot gap -> strictly > 0.
        const int k = 3 + tid;
        const float tk = t[k];
        float d[4][4];
        for (int j = 0; j < 4; ++j) {
            d[j][0] = cc[k - 3 + j];
            d[j][1] = d[j][2] = d[j][3] = 0.f;
        }
        for (int r = 1; r <= 3; ++r) {
            for (int j = 3; j >= r; --j) {
                const float tlo = t[k + j - 3];
                const float thi = t[k + j + 1 - r];
                const float B = 1.f / (thi - tlo);
                const float A = (tk - tlo) * B;
                float nd[4];
                for (int nn = 0; nn < 4; ++nn) nd[nn] = d[j - 1][nn];
                for (int nn = 0; nn < r; ++nn) {
                    const float en = d[j][nn] - d[j - 1][nn];
                    nd[nn]     += A * en;
                    nd[nn + 1] += B * en;
                }
                for (int nn = 0; nn < 4; ++nn) d[j][nn] = nd[nn];
            }
        }
        d3[tid] = d[3][3];
        if (tid == 0) {   // interval 0 has tk = 0 -> already expanded in x
            p0[0] = d[3][0]; p0[1] = d[3][1]; p0[2] = d[3][2]; p0[3] = d[3][3];
        }
    }
    __syncthreads();

    if (tid < 16) {
        float val;
        if (tid < 4)       val = p0[tid];
        else if (tid < 10) val = t[tid];                      // t[4..9] == k1..k6
        else               val = d3[tid - 9] - d3[tid - 10];  // e_{tid-9}
        P[tid] = val;
    }
    __syncthreads();

    // ---- broadcast params to registers (wave-uniform LDS reads) ----
    const float c0 = P[0],  c1 = P[1],  c2 = P[2],  c3 = P[3];
    const float k1 = P[4],  k2 = P[5],  k3 = P[6],  k4 = P[7],  k5 = P[8],  k6 = P[9];
    const float e1 = P[10], e2 = P[11], e3 = P[12], e4 = P[13], e5 = P[14], e6 = P[15];

    // ---- streaming eval ----
    const int n4 = n >> 2;
    const int gid = blockIdx.x * blockDim.x + tid;
    const int stride = gridDim.x * blockDim.x;

    const f4* __restrict__ x4 = reinterpret_cast<const f4*>(x);
    f4* __restrict__ o4 = reinterpret_cast<f4*>(out);

    const int pair = stride << 1;            // elements consumed per pair-round
    if ((n4 & (pair - 1)) == 0 || (n4 % pair) == 0) {
        // Fast path (exact at n=256^3): every thread runs n4/pair full rounds.
        const int rounds = n4 / pair;
        int i0 = gid;
        f4 a0 = x4[i0];
        f4 a1 = x4[i0 + stride];
        for (int kk = 1; kk < rounds; ++kk) {
            const int i1 = i0 + pair;
            const f4 b0 = x4[i1];             // issue next pair BEFORE using cur
            const f4 b1 = x4[i1 + stride];
            f4 r0, r1;
            EVAL4(r0, a0);
            EVAL4(r1, a1);
            __builtin_nontemporal_store(r0, o4 + i0);
            __builtin_nontemporal_store(r1, o4 + i0 + stride);
            a0 = b0; a1 = b1; i0 = i1;
        }
        f4 r0, r1;                            // epilogue
        EVAL4(r0, a0);
        EVAL4(r1, a1);
        __builtin_nontemporal_store(r0, o4 + i0);
        __builtin_nontemporal_store(r1, o4 + i0 + stride);
    } else {
        // General fallback: simple grid-stride loop.
        for (int idx = gid; idx < n4; idx += stride) {
            const f4 v = x4[idx];
            f4 r;
            EVAL4(r, v);
            __builtin_nontemporal_store(r, o4 + idx);
        }
    }
    // scalar tail (n % 4 != 0 safety; empty at n = 256^3)
    for (int j = (n4 << 2) + gid; j < n; j += stride)
        out[j] = eval_one(x[j], c0,c1,c2,c3, k1,k2,k3,k4,k5,k6, e1,e2,e3,e4,e5,e6);
}

extern "C" void kernel_launch(void* const* d_in, const int* in_sizes, int n_in,
                              void* d_out, int out_size, void* d_ws, size_t ws_size,
                              hipStream_t stream)
{
    const float* x  = (const float*)d_in[0];
    const float* a  = (const float*)d_in[1];
    const float* W1 = (const float*)d_in[2];
    const float* b1 = (const float*)d_in[3];
    const float* W2 = (const float*)d_in[4];
    const float* b2 = (const float*)d_in[5];
    const float* Ww = (const float*)d_in[6];
    const float* bw = (const float*)d_in[7];
    const float* Wk = (const float*)d_in[8];
    const float* bk = (const float*)d_in[9];
    float* out = (float*)d_out;
    const int n = out_size;

    // 1024 blocks x 256 = 4096 waves (16/CU): ample for streaming BW, half
    // the redundant prologues. 16 f4/thread in 8 pipelined pair-rounds.
    hipLaunchKernelGGL(nsf_fused_kernel, dim3(1024), dim3(256), 0, stream,
                       x, a, W1, b1, W2, b2, Ww, bw, Wk, bk, out, n);
}